// Round 8
// baseline (577.598 us; speedup 1.0000x reference)
//
#include <hip/hip_runtime.h>

// Problem constants (from reference)
#define B_  16
#define T_  2048
#define IN_ 512
#define H_  512
#define M_  (B_ * T_)

// GEMM tiling (R5 single-buffer structure — VGPR 116, 4 blocks/CU, 212us.
// R7's LDS ping-pong raised VGPR to 192 -> 298us. R6's (256,4) bound spilled
// acc to scratch -> 3048us. Keep THIS structure.)
#define BM 128
#define BN 128
#define BK 16
#define LDT (BM + 4)

// Fused producer-consumer structure
#define NTAU          16     // T split into 16 chunks of 128
#define TCHUNK        128
#define GEMM_PBLOCKS  512    // persistent producers: 2 tiles each, tau-ordered
#define SCAN_BLOCKS   32     // 8192 chains / 256
#define FLAGS_PER_TAU 64     // 16 b x 4 n tiles per tau

static __device__ __forceinline__ float4 ld4(const float* p) {
    return *reinterpret_cast<const float4*>(p);
}

// ---------------------------------------------------------------------------
// One GEMM tile: h[m0:m0+128][n0:n0+128] = X-tile . W-tile^T + b.
// k accumulated strictly in order 0..511 with fmaf -> bit-matches np ref
// (absmax 0.0 across R2-R7). DO NOT reorder the k loop.
// Single LDS buffer, register prefetch of next k-tile (R5 body, verbatim).
// ---------------------------------------------------------------------------
__device__ __forceinline__
void gemm_tile(const float* __restrict__ X, const float* __restrict__ W,
               const float* __restrict__ bias, float* __restrict__ Hout,
               float (*__restrict__ As)[LDT], float (*__restrict__ Bs)[LDT],
               int g, int* flags)
{
    const int tid = threadIdx.x;
    const int tau = g >> 6;
    const int idx = g & 63;
    const int bb  = idx >> 2;
    const int ni  = idx & 3;
    const int m0  = bb * T_ + tau * TCHUNK;
    const int n0  = ni * BN;

    const int tx = tid & 15;
    const int ty = tid >> 4;
    const int row = tid >> 2;
    const int kph = (tid & 3) * 4;

    const float* pa0 = X + (size_t)(m0 + row) * IN_ + kph;
    const float* pa1 = pa0 + (size_t)64 * IN_;
    const float* pb0 = W + (size_t)(n0 + row) * IN_ + kph;
    const float* pb1 = pb0 + (size_t)64 * IN_;

    float4 ra0 = ld4(pa0), ra1 = ld4(pa1), rb0 = ld4(pb0), rb1 = ld4(pb1);

    float acc[8][8];
#pragma unroll
    for (int i = 0; i < 8; ++i)
#pragma unroll
        for (int j = 0; j < 8; ++j) acc[i][j] = 0.0f;

    for (int k0 = 0; k0 < IN_; k0 += BK) {
        As[kph + 0][row]      = ra0.x;  As[kph + 1][row]      = ra0.y;
        As[kph + 2][row]      = ra0.z;  As[kph + 3][row]      = ra0.w;
        As[kph + 0][row + 64] = ra1.x;  As[kph + 1][row + 64] = ra1.y;
        As[kph + 2][row + 64] = ra1.z;  As[kph + 3][row + 64] = ra1.w;
        Bs[kph + 0][row]      = rb0.x;  Bs[kph + 1][row]      = rb0.y;
        Bs[kph + 2][row]      = rb0.z;  Bs[kph + 3][row]      = rb0.w;
        Bs[kph + 0][row + 64] = rb1.x;  Bs[kph + 1][row + 64] = rb1.y;
        Bs[kph + 2][row + 64] = rb1.z;  Bs[kph + 3][row + 64] = rb1.w;
        __syncthreads();

        if (k0 + BK < IN_) {
            ra0 = ld4(pa0 + k0 + BK);  ra1 = ld4(pa1 + k0 + BK);
            rb0 = ld4(pb0 + k0 + BK);  rb1 = ld4(pb1 + k0 + BK);
        }

#pragma unroll
        for (int k = 0; k < BK; ++k) {
            float4 av0 = ld4(&As[k][ty * 4]);
            float4 av1 = ld4(&As[k][ty * 4 + 64]);
            float4 bv0 = ld4(&Bs[k][tx * 4]);
            float4 bv1 = ld4(&Bs[k][tx * 4 + 64]);
            const float am[8] = {av0.x, av0.y, av0.z, av0.w,
                                 av1.x, av1.y, av1.z, av1.w};
            const float bn8[8] = {bv0.x, bv0.y, bv0.z, bv0.w,
                                  bv1.x, bv1.y, bv1.z, bv1.w};
#pragma unroll
            for (int i = 0; i < 8; ++i)
#pragma unroll
                for (int j = 0; j < 8; ++j)
                    acc[i][j] = fmaf(am[i], bn8[j], acc[i][j]);
        }
        __syncthreads();
    }

    float4 bb0 = ld4(&bias[n0 + tx * 4]);
    float4 bb1 = ld4(&bias[n0 + tx * 4 + 64]);
#pragma unroll
    for (int i = 0; i < 8; ++i) {
        const int r = m0 + ((i < 4) ? (ty * 4 + i) : (64 + ty * 4 + (i - 4)));
        float4 o0, o1;
        o0.x = acc[i][0] + bb0.x;  o0.y = acc[i][1] + bb0.y;
        o0.z = acc[i][2] + bb0.z;  o0.w = acc[i][3] + bb0.w;
        o1.x = acc[i][4] + bb1.x;  o1.y = acc[i][5] + bb1.y;
        o1.z = acc[i][6] + bb1.z;  o1.w = acc[i][7] + bb1.w;
        *reinterpret_cast<float4*>(&Hout[(size_t)r * H_ + n0 + tx * 4])      = o0;
        *reinterpret_cast<float4*>(&Hout[(size_t)r * H_ + n0 + tx * 4 + 64]) = o1;
    }

    if (flags) {
        __threadfence();            // h-stores device-visible before signal
        __syncthreads();
        if (tid == 0)
            __hip_atomic_fetch_add(&flags[tau], 1, __ATOMIC_RELEASE,
                                   __HIP_MEMORY_SCOPE_AGENT);
    }
}

// ---------------------------------------------------------------------------
// Scan: one thread per (b,h) chain. Step arithmetic + correctly-rounded div
// VERBATIM from R6 (bit-matches np ref, ~143us standalone). DO NOT touch.
// ---------------------------------------------------------------------------
#define SPF 32

__device__ __forceinline__
void scan_steps(const float* __restrict__ buf, float* __restrict__ sp,
                int tb, float& v, float& theta) {
    const float DECAY_F = 0.9048374180359595f;  // exp(-1/10)
    const float ALPHA_F = 0.01f;
#pragma unroll
    for (int j = 0; j < SPF; ++j) {
        float cur = buf[j];
        v = v * DECAY_F + cur;
        float cl = 32.0f * theta;                  // L * theta * 2
        v = __builtin_amdgcn_fmed3f(v, -cl, cl);   // == fminf(fmaxf(v,-cl),cl)

        // ---- correctly-rounded v/theta (bit-identical to IEEE div) ----
        float r0 = __builtin_amdgcn_rcpf(theta);
        float e0 = fmaf(-theta, r0, 1.0f);
        float r1 = fmaf(r0, e0, r0);
        float e1 = fmaf(-theta, r1, 1.0f);
        float r2 = fmaf(r1, e1, r1);
        float q0 = v * r2;
        float er = fmaf(-theta, q0, v);
        float q  = fmaf(er, r2, q0);
        // ---------------------------------------------------------------

        float s = floorf(q);
        s = __builtin_amdgcn_fmed3f(s, 0.0f, 16.0f);
        v = v - s * theta;
        theta = theta + ALPHA_F * s - ALPHA_F * (theta - 1.0f);
        sp[(size_t)(tb + j) * H_] = s;
    }
}

__device__ __forceinline__
void scan_chunk(const float* __restrict__ ip, float* __restrict__ sp,
                int tb, float& v, float& theta) {
    float bufA[SPF], bufB[SPF];
#pragma unroll
    for (int j = 0; j < SPF; ++j) bufA[j] = ip[(size_t)(tb + j) * H_];

#pragma unroll
    for (int j = 0; j < SPF; ++j) bufB[j] = ip[(size_t)(tb + SPF + j) * H_];
    asm volatile("" ::: "memory");
    scan_steps(bufA, sp, tb, v, theta);

#pragma unroll
    for (int j = 0; j < SPF; ++j) bufA[j] = ip[(size_t)(tb + 2 * SPF + j) * H_];
    asm volatile("" ::: "memory");
    scan_steps(bufB, sp, tb + SPF, v, theta);

#pragma unroll
    for (int j = 0; j < SPF; ++j) bufB[j] = ip[(size_t)(tb + 3 * SPF + j) * H_];
    asm volatile("" ::: "memory");
    scan_steps(bufA, sp, tb + 2 * SPF, v, theta);

    scan_steps(bufB, sp, tb + 3 * SPF, v, theta);
}

__device__ __forceinline__
void scan_body(const float* __restrict__ Hbuf, float* __restrict__ spikes,
               float* __restrict__ vout, float* __restrict__ thout,
               int sb, int* flags)
{
    const int tid = threadIdx.x;
    const int gid = sb * 256 + tid;       // 0..8191
    const int b = gid >> 9;
    const int h = gid & 511;

    const float* ip = Hbuf   + (size_t)b * T_ * H_ + h;
    float*       sp = spikes + (size_t)b * T_ * H_ + h;

    float v = 0.0f, theta = 1.0f;
    for (int tau = 0; tau < NTAU; ++tau) {
        if (flags) {
            if (tid == 0) {
                while (__hip_atomic_load(&flags[tau], __ATOMIC_ACQUIRE,
                                         __HIP_MEMORY_SCOPE_AGENT) < FLAGS_PER_TAU)
                    __builtin_amdgcn_s_sleep(8);
            }
            __syncthreads();
        }
        scan_chunk(ip, sp, tau * TCHUNK, v, theta);
    }
    vout[gid]  = v;
    thout[gid] = theta;
}

// ---------------------------------------------------------------------------
// Fused kernel: blocks 0..31 = scan consumers; 32..543 = persistent GEMM
// producers, 2 tiles each in tau-major order (iter 0 -> tau 0..7, iter 1 ->
// tau 8..15). All 544 blocks fit on-device simultaneously (<=4/CU capacity
// at VGPR 116), GEMM never waits on scan -> no deadlock.
// ---------------------------------------------------------------------------
__global__ __launch_bounds__(256)
void fused_kernel(const float* __restrict__ X, const float* __restrict__ W,
                  const float* __restrict__ bias, float* __restrict__ hbuf,
                  float* __restrict__ spikes, float* __restrict__ vf,
                  float* __restrict__ thf, int* flags)
{
    __shared__ float As[BK][LDT];
    __shared__ float Bs[BK][LDT];

    if ((int)blockIdx.x < SCAN_BLOCKS) {
        scan_body(hbuf, spikes, vf, thf, blockIdx.x, flags);
    } else {
        const int p = blockIdx.x - SCAN_BLOCKS;          // 0..511
        gemm_tile(X, W, bias, hbuf, As, Bs, p, flags);
        gemm_tile(X, W, bias, hbuf, As, Bs, GEMM_PBLOCKS + p, flags);
    }
}

// Fallback pair (ws too small for flags): serial two-kernel path
__global__ __launch_bounds__(256)
void gemm_kernel(const float* __restrict__ X, const float* __restrict__ W,
                 const float* __restrict__ bias, float* __restrict__ hbuf)
{
    __shared__ float As[BK][LDT];
    __shared__ float Bs[BK][LDT];
    gemm_tile(X, W, bias, hbuf, As, Bs, blockIdx.x, nullptr);
}

__global__ __launch_bounds__(256)
void scan_kernel(const float* __restrict__ hbuf, float* __restrict__ spikes,
                 float* __restrict__ vf, float* __restrict__ thf)
{
    scan_body(hbuf, spikes, vf, thf, blockIdx.x, nullptr);
}

// ---------------------------------------------------------------------------
extern "C" void kernel_launch(void* const* d_in, const int* in_sizes, int n_in,
                              void* d_out, int out_size, void* d_ws, size_t ws_size,
                              hipStream_t stream) {
    const float* x    = (const float*)d_in[0];   // [16, 2048, 512]
    const float* W    = (const float*)d_in[1];   // [512, 512]
    const float* bias = (const float*)d_in[2];   // [512]

    float* out    = (float*)d_out;
    float* spikes = out;
    float* v_f    = out + (size_t)M_ * H_;
    float* th_f   = v_f + (size_t)B_ * H_;

    float* hbuf   = (float*)d_ws;                // 64 MiB scratch for h
    const size_t hbytes = (size_t)M_ * H_ * sizeof(float);

    if (ws_size >= hbytes + NTAU * sizeof(int)) {
        int* flags = (int*)((char*)d_ws + hbytes);
        hipMemsetAsync(flags, 0, NTAU * sizeof(int), stream);
        fused_kernel<<<SCAN_BLOCKS + GEMM_PBLOCKS, 256, 0, stream>>>(
            x, W, bias, hbuf, spikes, v_f, th_f, flags);
    } else {
        gemm_kernel<<<1024, 256, 0, stream>>>(x, W, bias, hbuf);
        scan_kernel<<<SCAN_BLOCKS, 256, 0, stream>>>(hbuf, spikes, v_f, th_f);
    }
}

// Round 9
// 397.728 us; speedup vs baseline: 1.4522x; 1.4522x over previous
//
#include <hip/hip_runtime.h>

// Problem constants (from reference)
#define B_  16
#define T_  2048
#define IN_ 512
#define H_  512
#define M_  (B_ * T_)

// GEMM tiling. History: R5 single-buffer = 212us (VGPR 116, 4 blk/CU).
// R6 (256,4) bound -> acc spilled -> 3048us. R7 2-reg-set ping-pong ->
// VGPR 192 -> 298us. R8 fusion -> occupancy coupling -> 529us. This round:
// ping-pong LDS, ONE barrier/tile, ONE staging register set (loads issued
// at tile top, staged mid-compute between the two k-halves).
#define BM 128
#define BN 128
#define BK 16
#define LDT (BM + 4)

static __device__ __forceinline__ float4 ld4(const float* p) {
    return *reinterpret_cast<const float4*>(p);
}

// ---------------------------------------------------------------------------
// Kernel 1: h[m][n] = sum_k x[m][k]*W[n][k] + b[n], fp32 VALU.
// k accumulated strictly in order 0..511 with fmaf -> bit-matches np ref
// (absmax 0.0 across R2-R8). DO NOT reorder the k loop.
// ---------------------------------------------------------------------------

__device__ __forceinline__
void stage_to_lds(float (*__restrict__ Asb)[LDT], float (*__restrict__ Bsb)[LDT],
                  const float4& ra0, const float4& ra1,
                  const float4& rb0, const float4& rb1, int row, int kph) {
    Asb[kph + 0][row]      = ra0.x;  Asb[kph + 1][row]      = ra0.y;
    Asb[kph + 2][row]      = ra0.z;  Asb[kph + 3][row]      = ra0.w;
    Asb[kph + 0][row + 64] = ra1.x;  Asb[kph + 1][row + 64] = ra1.y;
    Asb[kph + 2][row + 64] = ra1.z;  Asb[kph + 3][row + 64] = ra1.w;
    Bsb[kph + 0][row]      = rb0.x;  Bsb[kph + 1][row]      = rb0.y;
    Bsb[kph + 2][row]      = rb0.z;  Bsb[kph + 3][row]      = rb0.w;
    Bsb[kph + 0][row + 64] = rb1.x;  Bsb[kph + 1][row + 64] = rb1.y;
    Bsb[kph + 2][row + 64] = rb1.z;  Bsb[kph + 3][row + 64] = rb1.w;
}

// compute k = klo..khi-1 of the tile (strict ascending k order preserved)
__device__ __forceinline__
void compute_half(const float (*__restrict__ Asb)[LDT],
                  const float (*__restrict__ Bsb)[LDT],
                  float acc[8][8], int tx, int ty, int klo, int khi) {
#pragma unroll
    for (int k = klo; k < khi; ++k) {
        float4 av0 = ld4(&Asb[k][ty * 4]);
        float4 av1 = ld4(&Asb[k][ty * 4 + 64]);
        float4 bv0 = ld4(&Bsb[k][tx * 4]);
        float4 bv1 = ld4(&Bsb[k][tx * 4 + 64]);
        const float am[8] = {av0.x, av0.y, av0.z, av0.w,
                             av1.x, av1.y, av1.z, av1.w};
        const float bn8[8] = {bv0.x, bv0.y, bv0.z, bv0.w,
                              bv1.x, bv1.y, bv1.z, bv1.w};
#pragma unroll
        for (int i = 0; i < 8; ++i)
#pragma unroll
            for (int j = 0; j < 8; ++j)
                acc[i][j] = fmaf(am[i], bn8[j], acc[i][j]);
    }
}

__global__ __launch_bounds__(256)
void gemm_xwT(const float* __restrict__ X, const float* __restrict__ W,
              const float* __restrict__ bias, float* __restrict__ Hout) {
    __shared__ float As[2][BK][LDT];
    __shared__ float Bs[2][BK][LDT];

    const int tid = threadIdx.x;
    const int m0  = blockIdx.x * BM;   // 256 m-tiles
    const int n0  = blockIdx.y * BN;   // 4 n-tiles

    const int tx = tid & 15;
    const int ty = tid >> 4;
    const int row = tid >> 2;          // 0..63
    const int kph = (tid & 3) * 4;     // 0,4,8,12

    const float* pa0 = X + (size_t)(m0 + row) * IN_ + kph;
    const float* pa1 = pa0 + (size_t)64 * IN_;
    const float* pb0 = W + (size_t)(n0 + row) * IN_ + kph;
    const float* pb1 = pb0 + (size_t)64 * IN_;

    float acc[8][8];
#pragma unroll
    for (int i = 0; i < 8; ++i)
#pragma unroll
        for (int j = 0; j < 8; ++j) acc[i][j] = 0.0f;

    // prologue: tile 0 -> buf 0
    float4 ra0 = ld4(pa0), ra1 = ld4(pa1), rb0 = ld4(pb0), rb1 = ld4(pb1);
    stage_to_lds(As[0], Bs[0], ra0, ra1, rb0, rb1, row, kph);
    __syncthreads();

    int buf = 0;
#pragma unroll 1
    for (int k0 = 0; k0 < IN_; k0 += BK) {
        const int kn = k0 + BK;
        const bool more = (kn < IN_);
        if (more) {                        // issue next tile's loads now
            ra0 = ld4(pa0 + kn);  ra1 = ld4(pa1 + kn);
            rb0 = ld4(pb0 + kn);  rb1 = ld4(pb1 + kn);
        }
        asm volatile("" ::: "memory");     // pin load issue before compute
        compute_half(As[buf], Bs[buf], acc, tx, ty, 0, 8);
        if (more)                          // vmcnt mostly drained by now
            stage_to_lds(As[buf ^ 1], Bs[buf ^ 1], ra0, ra1, rb0, rb1, row, kph);
        compute_half(As[buf], Bs[buf], acc, tx, ty, 8, 16);
        __syncthreads();                   // ONE barrier per tile
        buf ^= 1;
    }

    // epilogue: + bias (bias is zeros -> exact), coalesced float4 stores
    float4 bb0 = ld4(&bias[n0 + tx * 4]);
    float4 bb1 = ld4(&bias[n0 + tx * 4 + 64]);
#pragma unroll
    for (int i = 0; i < 8; ++i) {
        const int r = m0 + ((i < 4) ? (ty * 4 + i) : (64 + ty * 4 + (i - 4)));
        float4 o0, o1;
        o0.x = acc[i][0] + bb0.x;  o0.y = acc[i][1] + bb0.y;
        o0.z = acc[i][2] + bb0.z;  o0.w = acc[i][3] + bb0.w;
        o1.x = acc[i][4] + bb1.x;  o1.y = acc[i][5] + bb1.y;
        o1.z = acc[i][6] + bb1.z;  o1.w = acc[i][7] + bb1.w;
        *reinterpret_cast<float4*>(&Hout[(size_t)r * H_ + n0 + tx * 4])      = o0;
        *reinterpret_cast<float4*>(&Hout[(size_t)r * H_ + n0 + tx * 4 + 64]) = o1;
    }
}

// ---------------------------------------------------------------------------
// Kernel 2: GIF neuron scan — byte-identical to the R7/R8 scan (139us
// standalone). One thread per (b,h) chain; wall = 2048 x chain period
// (~163 cyc). Update expressions + correctly-rounded div bit-match np
// (absmax 0.0). DO NOT touch the arithmetic statements.
// ---------------------------------------------------------------------------
#define SPF 32

__device__ __forceinline__
void scan_steps(const float* __restrict__ buf, float* __restrict__ sp,
                int tb, float& v, float& theta) {
    const float DECAY_F = 0.9048374180359595f;  // exp(-1/10)
    const float ALPHA_F = 0.01f;
#pragma unroll
    for (int j = 0; j < SPF; ++j) {
        float cur = buf[j];
        v = v * DECAY_F + cur;
        float cl = 32.0f * theta;                  // L * theta * 2
        v = __builtin_amdgcn_fmed3f(v, -cl, cl);   // == fminf(fmaxf(v,-cl),cl)

        // ---- correctly-rounded v/theta (bit-identical to IEEE div) ----
        float r0 = __builtin_amdgcn_rcpf(theta);
        float e0 = fmaf(-theta, r0, 1.0f);
        float r1 = fmaf(r0, e0, r0);
        float e1 = fmaf(-theta, r1, 1.0f);
        float r2 = fmaf(r1, e1, r1);
        float q0 = v * r2;
        float er = fmaf(-theta, q0, v);
        float q  = fmaf(er, r2, q0);
        // ---------------------------------------------------------------

        float s = floorf(q);
        s = __builtin_amdgcn_fmed3f(s, 0.0f, 16.0f);
        v = v - s * theta;
        theta = theta + ALPHA_F * s - ALPHA_F * (theta - 1.0f);
        sp[(size_t)(tb + j) * H_] = s;
    }
}

__global__ __launch_bounds__(64)
void gif_scan(const float* __restrict__ Hbuf, float* __restrict__ spikes,
              float* __restrict__ vout, float* __restrict__ thout) {
    const int gid = blockIdx.x * 64 + threadIdx.x;    // 0..8191
    const int b = gid >> 9;
    const int h = gid & 511;

    const float* ip = Hbuf   + (size_t)b * T_ * H_ + h;
    float*       sp = spikes + (size_t)b * T_ * H_ + h;

    float bufA[SPF], bufB[SPF];
#pragma unroll
    for (int j = 0; j < SPF; ++j) bufA[j] = ip[(size_t)j * H_];

    float v = 0.0f, theta = 1.0f;
    for (int t0 = 0; t0 < T_; t0 += 2 * SPF) {        // 32 iters, no tail
#pragma unroll
        for (int j = 0; j < SPF; ++j) bufB[j] = ip[(size_t)(t0 + SPF + j) * H_];
        asm volatile("" ::: "memory");
        scan_steps(bufA, sp, t0, v, theta);

        if (t0 + 2 * SPF < T_) {
#pragma unroll
            for (int j = 0; j < SPF; ++j)
                bufA[j] = ip[(size_t)(t0 + 2 * SPF + j) * H_];
        }
        asm volatile("" ::: "memory");
        scan_steps(bufB, sp, t0 + SPF, v, theta);
    }
    vout[gid]  = v;
    thout[gid] = theta;
}

// ---------------------------------------------------------------------------
extern "C" void kernel_launch(void* const* d_in, const int* in_sizes, int n_in,
                              void* d_out, int out_size, void* d_ws, size_t ws_size,
                              hipStream_t stream) {
    const float* x    = (const float*)d_in[0];   // [16, 2048, 512]
    const float* W    = (const float*)d_in[1];   // [512, 512]
    const float* bias = (const float*)d_in[2];   // [512]

    float* out    = (float*)d_out;
    float* spikes = out;
    float* v_f    = out + (size_t)M_ * H_;
    float* th_f   = v_f + (size_t)B_ * H_;

    float* hbuf   = (float*)d_ws;                // 64 MiB scratch for h

    dim3 grid(M_ / BM, H_ / BN);                 // 256 x 4
    gemm_xwT<<<grid, 256, 0, stream>>>(x, W, bias, hbuf);
    gif_scan<<<(B_ * H_) / 64, 64, 0, stream>>>(hbuf, spikes, v_f, th_f);
}

// Round 10
// 370.237 us; speedup vs baseline: 1.5601x; 1.0743x over previous
//
#include <hip/hip_runtime.h>

// Problem constants (from reference)
#define B_  16
#define T_  2048
#define IN_ 512
#define H_  512
#define M_  (B_ * T_)

// GEMM tiling — R5 structure, the measured local optimum (212us, VGPR 116).
// History: R6 (256,4) bound -> acc spill -> 3048us. R7 2-reg-set ping-pong
// -> VGPR 192 -> 298us. R8 persistent fusion -> occupancy coupling -> 529us.
// R9 1-barrier ping-pong -> mid-compute vmcnt drain -> 230us. KEEP THIS.
#define BM 128
#define BN 128
#define BK 16
#define LDT (BM + 4)

static __device__ __forceinline__ float4 ld4(const float* p) {
    return *reinterpret_cast<const float4*>(p);
}

// ---------------------------------------------------------------------------
// Kernel 1: h[m][n] = sum_k x[m][k]*W[n][k] + b[n], fp32 VALU.
// k accumulated strictly in order 0..511 with fmaf -> bit-matches np ref
// (absmax 0.0 across R2-R9). DO NOT reorder the k loop.
// Single LDS buffer + register prefetch of next k-tile (R5 body, verbatim).
// ---------------------------------------------------------------------------
__global__ __launch_bounds__(256)
void gemm_xwT(const float* __restrict__ X, const float* __restrict__ W,
              const float* __restrict__ bias, float* __restrict__ Hout) {
    __shared__ float As[BK][LDT];
    __shared__ float Bs[BK][LDT];

    const int tid = threadIdx.x;
    const int m0  = blockIdx.x * BM;   // 256 m-tiles
    const int n0  = blockIdx.y * BN;   // 4 n-tiles

    const int tx = tid & 15;           // col group
    const int ty = tid >> 4;           // row group

    const int row = tid >> 2;          // 0..63
    const int kph = (tid & 3) * 4;     // 0,4,8,12

    const float* pa0 = X + (size_t)(m0 + row) * IN_ + kph;
    const float* pa1 = pa0 + (size_t)64 * IN_;
    const float* pb0 = W + (size_t)(n0 + row) * IN_ + kph;
    const float* pb1 = pb0 + (size_t)64 * IN_;

    float4 ra0 = ld4(pa0), ra1 = ld4(pa1), rb0 = ld4(pb0), rb1 = ld4(pb1);

    float acc[8][8];
#pragma unroll
    for (int i = 0; i < 8; ++i)
#pragma unroll
        for (int j = 0; j < 8; ++j) acc[i][j] = 0.0f;

    for (int k0 = 0; k0 < IN_; k0 += BK) {
        As[kph + 0][row]      = ra0.x;  As[kph + 1][row]      = ra0.y;
        As[kph + 2][row]      = ra0.z;  As[kph + 3][row]      = ra0.w;
        As[kph + 0][row + 64] = ra1.x;  As[kph + 1][row + 64] = ra1.y;
        As[kph + 2][row + 64] = ra1.z;  As[kph + 3][row + 64] = ra1.w;
        Bs[kph + 0][row]      = rb0.x;  Bs[kph + 1][row]      = rb0.y;
        Bs[kph + 2][row]      = rb0.z;  Bs[kph + 3][row]      = rb0.w;
        Bs[kph + 0][row + 64] = rb1.x;  Bs[kph + 1][row + 64] = rb1.y;
        Bs[kph + 2][row + 64] = rb1.z;  Bs[kph + 3][row + 64] = rb1.w;
        __syncthreads();

        // prefetch next k-tile into registers; drains during the 16-k compute
        if (k0 + BK < IN_) {
            ra0 = ld4(pa0 + k0 + BK);  ra1 = ld4(pa1 + k0 + BK);
            rb0 = ld4(pb0 + k0 + BK);  rb1 = ld4(pb1 + k0 + BK);
        }

#pragma unroll
        for (int k = 0; k < BK; ++k) {
            float4 av0 = ld4(&As[k][ty * 4]);
            float4 av1 = ld4(&As[k][ty * 4 + 64]);
            float4 bv0 = ld4(&Bs[k][tx * 4]);
            float4 bv1 = ld4(&Bs[k][tx * 4 + 64]);
            const float am[8] = {av0.x, av0.y, av0.z, av0.w,
                                 av1.x, av1.y, av1.z, av1.w};
            const float bn8[8] = {bv0.x, bv0.y, bv0.z, bv0.w,
                                  bv1.x, bv1.y, bv1.z, bv1.w};
#pragma unroll
            for (int i = 0; i < 8; ++i)
#pragma unroll
                for (int j = 0; j < 8; ++j)
                    acc[i][j] = fmaf(am[i], bn8[j], acc[i][j]);
        }
        __syncthreads();
    }

    // epilogue: + bias (bias is zeros -> exact), coalesced float4 stores
    float4 bb0 = ld4(&bias[n0 + tx * 4]);
    float4 bb1 = ld4(&bias[n0 + tx * 4 + 64]);
#pragma unroll
    for (int i = 0; i < 8; ++i) {
        const int r = m0 + ((i < 4) ? (ty * 4 + i) : (64 + ty * 4 + (i - 4)));
        float4 o0, o1;
        o0.x = acc[i][0] + bb0.x;  o0.y = acc[i][1] + bb0.y;
        o0.z = acc[i][2] + bb0.z;  o0.w = acc[i][3] + bb0.w;
        o1.x = acc[i][4] + bb1.x;  o1.y = acc[i][5] + bb1.y;
        o1.z = acc[i][6] + bb1.z;  o1.w = acc[i][7] + bb1.w;
        *reinterpret_cast<float4*>(&Hout[(size_t)r * H_ + n0 + tx * 4])      = o0;
        *reinterpret_cast<float4*>(&Hout[(size_t)r * H_ + n0 + tx * 4 + 64]) = o1;
    }
}

// ---------------------------------------------------------------------------
// Kernel 2: GIF neuron scan. One thread per (b,h) chain; T=2048 steps.
// Wall = 2048 x dependent-chain period. Change vs R7/R9 scan: the div uses
// ONE Newton-Raphson step instead of two. Rationale: after 1 N-R from the
// ~1-ulp v_rcp seed, rel err = eps0^2 ~ 1.4e-14 + r1's own 0.5-ulp rounding,
// so r1 is already the (essentially) correctly-rounded reciprocal; the R5-R9
// second N-R re-rounded back to r1 (validated by absmax 0.0 on 16.7M divs).
// Everything else byte-identical to the R7/R9 scan. DO NOT touch the
// arithmetic statements.
// ---------------------------------------------------------------------------
#define SPF 32

__device__ __forceinline__
void scan_steps(const float* __restrict__ buf, float* __restrict__ sp,
                int tb, float& v, float& theta) {
    const float DECAY_F = 0.9048374180359595f;  // exp(-1/10)
    const float ALPHA_F = 0.01f;
#pragma unroll
    for (int j = 0; j < SPF; ++j) {
        float cur = buf[j];
        v = v * DECAY_F + cur;
        float cl = 32.0f * theta;                  // L * theta * 2
        v = __builtin_amdgcn_fmed3f(v, -cl, cl);   // == fminf(fmaxf(v,-cl),cl)

        // ---- correctly-rounded v/theta: rcp + 1 N-R + Markstein ----
        float r0 = __builtin_amdgcn_rcpf(theta);   // ~1 ulp
        float e0 = fmaf(-theta, r0, 1.0f);
        float r1 = fmaf(r0, e0, r0);               // ~0.5 ulp reciprocal
        float q0 = v * r1;
        float er = fmaf(-theta, q0, v);            // exact residual
        float q  = fmaf(er, r1, q0);               // correctly-rounded quotient
        // ------------------------------------------------------------

        float s = floorf(q);
        s = __builtin_amdgcn_fmed3f(s, 0.0f, 16.0f); // == fminf(fmaxf(s,0),16)
        v = v - s * theta;
        theta = theta + ALPHA_F * s - ALPHA_F * (theta - 1.0f);
        sp[(size_t)(tb + j) * H_] = s;
    }
}

__global__ __launch_bounds__(64)
void gif_scan(const float* __restrict__ Hbuf, float* __restrict__ spikes,
              float* __restrict__ vout, float* __restrict__ thout) {
    const int gid = blockIdx.x * 64 + threadIdx.x;    // 0..8191
    const int b = gid >> 9;
    const int h = gid & 511;

    const float* ip = Hbuf   + (size_t)b * T_ * H_ + h;
    float*       sp = spikes + (size_t)b * T_ * H_ + h;

    float bufA[SPF], bufB[SPF];
#pragma unroll
    for (int j = 0; j < SPF; ++j) bufA[j] = ip[(size_t)j * H_];

    float v = 0.0f, theta = 1.0f;
    for (int t0 = 0; t0 < T_; t0 += 2 * SPF) {        // 32 iters, no tail
#pragma unroll
        for (int j = 0; j < SPF; ++j) bufB[j] = ip[(size_t)(t0 + SPF + j) * H_];
        asm volatile("" ::: "memory");
        scan_steps(bufA, sp, t0, v, theta);

        if (t0 + 2 * SPF < T_) {
#pragma unroll
            for (int j = 0; j < SPF; ++j)
                bufA[j] = ip[(size_t)(t0 + 2 * SPF + j) * H_];
        }
        asm volatile("" ::: "memory");
        scan_steps(bufB, sp, t0 + SPF, v, theta);
    }
    vout[gid]  = v;
    thout[gid] = theta;
}

// ---------------------------------------------------------------------------
extern "C" void kernel_launch(void* const* d_in, const int* in_sizes, int n_in,
                              void* d_out, int out_size, void* d_ws, size_t ws_size,
                              hipStream_t stream) {
    const float* x    = (const float*)d_in[0];   // [16, 2048, 512]
    const float* W    = (const float*)d_in[1];   // [512, 512]
    const float* bias = (const float*)d_in[2];   // [512]

    float* out    = (float*)d_out;
    float* spikes = out;
    float* v_f    = out + (size_t)M_ * H_;
    float* th_f   = v_f + (size_t)B_ * H_;

    float* hbuf   = (float*)d_ws;                // 64 MiB scratch for h

    dim3 grid(M_ / BM, H_ / BN);                 // 256 x 4
    gemm_xwT<<<grid, 256, 0, stream>>>(x, W, bias, hbuf);
    gif_scan<<<(B_ * H_) / 64, 64, 0, stream>>>(hbuf, spikes, v_f, th_f);
}